// Round 5
// baseline (15.764 us; speedup 1.0000x reference)
//
#include <hip/hip_runtime.h>

// CurveEval3: cubic B-spline curve evaluation, faithful to the NumPy
// reference (blowup-sensitive degenerate-knot regions).
// B=4096 curves, M=128 ctrl pts, p=3, OUT_DIM=256 samples, DIM=3. KNOTS=132.
//
// Bitwise-critical pieces (kept exact): u (np.linspace f64 replication),
// span selection (argmin FIRST-index tie-break), dU = (U1-u)+(u-U2) with
// _rn ops + dU==0.0f check. Division via v_rcp_f32 (1-ULP relative, safe
// under the 0.088 absmax threshold; verified absmax 0.0156 rounds 2-4).
//
// Structure: one block = one curve x 256 samples (best measured variant).
// Branchless 8-step span search; ctrl-point gathers issued right after the
// span so ds_read latency overlaps the recurrence VALU chain.

#define B_N     4096
#define M_N     128
#define P_DEG   3
#define T_N     256
#define KNOTS_N 132

__global__ __launch_bounds__(256) void curve_eval_kernel(
    const float* __restrict__ ctrl,   // (B, M, 3)
    const float* __restrict__ knots,  // (B, 132)
    float* __restrict__ out)          // (B, 256, 3)
{
    __shared__ float Uk[KNOTS_N];        // 132 floats
    __shared__ float cp[M_N * 4];        // rows padded to 4 -> ds_read_b128

    const int b = blockIdx.x;
    const int t = threadIdx.x;

    // ---- staging (vectorized, coalesced) ----
    if (t < 33) {
        ((float4*)Uk)[t] = ((const float4*)(knots + (size_t)b * KNOTS_N))[t];
    }
    if (t < 96) {
        float4 v = ((const float4*)(ctrl + (size_t)b * (M_N * 3)))[t];
        const int e = t * 4;
        cp[((e + 0) / 3) * 4 + (e + 0) % 3] = v.x;
        cp[((e + 1) / 3) * 4 + (e + 1) % 3] = v.y;
        cp[((e + 2) / 3) * 4 + (e + 2) % 3] = v.z;
        cp[((e + 3) / 3) * 4 + (e + 3) % 3] = v.w;
    }

    // ---- u = np.linspace(1e-5, 1-1e-5, 256) bitwise (f64 then round) ----
    // (computed before the barrier: overlaps staging-load latency)
    const double start = 1e-5;
    const double stop  = 1.0 - 1e-5;
    const double step  = (stop - start) / 255.0;
    float u;
    if (t == T_N - 1) u = (float)stop;
    else              u = (float)((double)t * step + start);

    __syncthreads();

    // ---- span: branchless fixed 8-step binary search ----
    // cond(i) = fl(u - Uk[3+i]) > 1e-8 is a true-prefix in i (knots sorted,
    // fl monotone); cond(0) always true (u >= 1e-5). Find LAST true in
    // [0,128]; then np.argmin FIRST-index tie-break via rare-path walk-back.
    int lo = 0;
    #pragma unroll
    for (int s = 128; s >= 1; s >>= 1) {
        const int cand = lo + s;
        const int idx  = cand <= 128 ? cand : 128;
        const float d  = __fsub_rn(u, Uk[P_DEG + idx]);
        if (cand <= 128 && d > 1e-8f) lo = cand;
    }
    if (lo > 0) {
        const float dmin = __fsub_rn(u, Uk[P_DEG + lo]);
        if (__fsub_rn(u, Uk[P_DEG + lo - 1]) == dmin) {
            do { --lo; } while (lo > 0 &&
                __fsub_rn(u, Uk[P_DEG + lo - 1]) == dmin);
        }
    }
    const int span = lo + P_DEG;   // uspan, in [3, 127]

    // ---- issue gathers first: 4x ds_read_b128 latency hides under the
    // recurrence VALU chain below ----
    const float4 c0 = *(const float4*)&cp[(span - 3) * 4];
    const float4 c1 = *(const float4*)&cp[(span - 2) * 4];
    const float4 c2 = *(const float4*)&cp[(span - 1) * 4];
    const float4 c3 = *(const float4*)&cp[(span - 0) * 4];

    // ---- knot window into registers ----
    const float w0 = Uk[span - 2];
    const float w1 = Uk[span - 1];
    const float w2 = Uk[span];
    const float w3 = Uk[span + 1];
    const float w4 = Uk[span + 2];
    const float w5 = Uk[span + 3];

    const float A1 = __fsub_rn(w3, u);
    const float A2 = __fsub_rn(w4, u);
    const float A3 = __fsub_rn(w5, u);
    const float B0 = __fsub_rn(u, w0);
    const float B1 = __fsub_rn(u, w1);
    const float B2 = __fsub_rn(u, w2);

    // temp = (dU==0) ? 1e-4 : N * rcp(dU)
    #define TDIV(N_, a1_, a2_, OUT_)                                    \
        {                                                               \
            const float dU = __fadd_rn(a1_, a2_);                       \
            float tmp = __fmul_rn((N_), __builtin_amdgcn_rcpf(dU));     \
            if (dU == 0.0f) tmp = 1e-4f;                                \
            OUT_ = tmp;                                                 \
        }

    float t0, t1, t2;
    float N0, N1, N2, N3, saved;
    // k=1
    TDIV(1.0f, A1, B2, t0);
    N0 = __fmul_rn(A1, t0);
    N1 = __fmul_rn(B2, t0);
    // k=2
    TDIV(N0, A1, B1, t0);
    TDIV(N1, A2, B2, t1);
    N0    = __fmul_rn(A1, t0);
    saved = __fmul_rn(B1, t0);
    N1    = __fadd_rn(saved, __fmul_rn(A2, t1));
    N2    = __fmul_rn(B2, t1);
    // k=3
    TDIV(N0, A1, B0, t0);
    TDIV(N1, A2, B1, t1);
    TDIV(N2, A3, B2, t2);
    N0    = __fmul_rn(A1, t0);
    saved = __fmul_rn(B0, t0);
    N1    = __fadd_rn(saved, __fmul_rn(A2, t1));
    saved = __fmul_rn(B1, t1);
    N2    = __fadd_rn(saved, __fmul_rn(A3, t2));
    N3    = __fmul_rn(B2, t2);
    #undef TDIV

    // ---- dot with the 4 gathered rows ----
    float acc0, acc1, acc2;
    acc0 = __fmul_rn(N0, c0.x);
    acc1 = __fmul_rn(N0, c0.y);
    acc2 = __fmul_rn(N0, c0.z);
    acc0 = __fadd_rn(acc0, __fmul_rn(N1, c1.x));
    acc1 = __fadd_rn(acc1, __fmul_rn(N1, c1.y));
    acc2 = __fadd_rn(acc2, __fmul_rn(N1, c1.z));
    acc0 = __fadd_rn(acc0, __fmul_rn(N2, c2.x));
    acc1 = __fadd_rn(acc1, __fmul_rn(N2, c2.y));
    acc2 = __fadd_rn(acc2, __fmul_rn(N2, c2.z));
    acc0 = __fadd_rn(acc0, __fmul_rn(N3, c3.x));
    acc1 = __fadd_rn(acc1, __fmul_rn(N3, c3.y));
    acc2 = __fadd_rn(acc2, __fmul_rn(N3, c3.z));

    float* o = out + ((size_t)b * T_N + t) * 3;
    o[0] = acc0;
    o[1] = acc1;
    o[2] = acc2;
}

extern "C" void kernel_launch(void* const* d_in, const int* in_sizes, int n_in,
                              void* d_out, int out_size, void* d_ws, size_t ws_size,
                              hipStream_t stream) {
    const float* ctrl  = (const float*)d_in[0];   // (4096, 128, 3) f32
    const float* knots = (const float*)d_in[1];   // (4096, 132)   f32
    float* out = (float*)d_out;                   // (4096, 256, 3) f32

    curve_eval_kernel<<<dim3(B_N), dim3(T_N), 0, stream>>>(ctrl, knots, out);
}

// Round 6
// 11.985 us; speedup vs baseline: 1.3153x; 1.3153x over previous
//
#include <hip/hip_runtime.h>

// CurveEval3: cubic B-spline curve evaluation, faithful to the NumPy
// reference (which has blowup-sensitive degenerate-knot regions).
// B=4096 curves, M=128 ctrl pts, p=3, OUT_DIM=256 samples, DIM=3. KNOTS=132.
//
// Bitwise-critical pieces (kept exact): u (np.linspace f64 replication),
// span selection (argmin FIRST-index tie-break), dU = (U1-u)+(u-w2) with
// _rn ops + dU==0.0f check. Non-critical rounding (division) uses v_rcp_f32
// — relative 1-ULP perturbation, safe under the 0.088 absmax threshold.
//
// This is the round-3 source verbatim — best measured variant (11.87 µs).
// Round-4 (4 curves/block) and round-5 (masked branchless search + early
// gathers) both regressed; see session journal.

#define B_N     4096
#define M_N     128
#define P_DEG   3
#define T_N     256
#define KNOTS_N 132

__global__ __launch_bounds__(256) void curve_eval_kernel(
    const float* __restrict__ ctrl,   // (B, M, 3)
    const float* __restrict__ knots,  // (B, 132)
    float* __restrict__ out)          // (B, 256, 3)
{
    __shared__ float Uk[KNOTS_N];        // 132 floats
    __shared__ float cp[M_N * 4];        // rows padded to 4 -> ds_read_b128

    const int b = blockIdx.x;
    const int t = threadIdx.x;

    // ---- staging (vectorized, coalesced) ----
    // knots: 132 floats = 33 float4 (row base b*528B is 16B-aligned)
    if (t < 33) {
        ((float4*)Uk)[t] = ((const float4*)(knots + (size_t)b * KNOTS_N))[t];
    }
    // ctrl: 384 floats = 96 float4; scatter into padded LDS rows
    if (t < 96) {
        float4 v = ((const float4*)(ctrl + (size_t)b * (M_N * 3)))[t];
        int i = t * 4;
        cp[((i + 0) / 3) * 4 + (i + 0) % 3] = v.x;
        cp[((i + 1) / 3) * 4 + (i + 1) % 3] = v.y;
        cp[((i + 2) / 3) * 4 + (i + 2) % 3] = v.z;
        cp[((i + 3) / 3) * 4 + (i + 3) % 3] = v.w;
    }
    __syncthreads();

    // ---- u = np.linspace(1e-5, 1-1e-5, 256) bitwise (f64 then round) ----
    const double start = 1e-5;
    const double stop  = 1.0 - 1e-5;
    const double step  = (stop - start) / 255.0;
    float u;
    if (t == T_N - 1) u = (float)stop;
    else              u = (float)((double)t * step + start);

    // ---- span: argmin over masked d = fl(u - U[p+i]), FIRST-index ties ----
    // d non-increasing in i; min positive d at LAST i with d > 1e-8, then
    // walk back over bitwise-equal-d ties (np.argmin takes the first).
    int lo = 0, hi = 128;
    while (lo < hi) {
        int mid = (lo + hi + 1) >> 1;
        float d = __fsub_rn(u, Uk[P_DEG + mid]);
        if (d > 1e-8f) lo = mid; else hi = mid - 1;
    }
    {
        const float dmin = __fsub_rn(u, Uk[P_DEG + lo]);
        while (lo > 0 && __fsub_rn(u, Uk[P_DEG + lo - 1]) == dmin) --lo;
    }
    const int span = lo + P_DEG;   // uspan, in [3, 127]

    // ---- knot window into registers (single LDS reads) ----
    const float w0 = Uk[span - 2];
    const float w1 = Uk[span - 1];
    const float w2 = Uk[span];
    const float w3 = Uk[span + 1];
    const float w4 = Uk[span + 2];
    const float w5 = Uk[span + 3];

    // a-terms, computed once with reference rounding
    const float A1 = __fsub_rn(w3, u);   // U[s+1]-u
    const float A2 = __fsub_rn(w4, u);   // U[s+2]-u
    const float A3 = __fsub_rn(w5, u);   // U[s+3]-u
    const float B0 = __fsub_rn(u, w0);   // u-U[s-2]
    const float B1 = __fsub_rn(u, w1);   // u-U[s-1]
    const float B2 = __fsub_rn(u, w2);   // u-U[s]

    // temp = (dU==0) ? 1e-4 : N * rcp(dU)   (division via v_rcp_f32)
    #define TDIV(N_, a1_, a2_, OUT_)                                    \
        {                                                               \
            const float dU = __fadd_rn(a1_, a2_);                       \
            float tmp = __fmul_rn((N_), __builtin_amdgcn_rcpf(dU));     \
            if (dU == 0.0f) tmp = 1e-4f;                                \
            OUT_ = tmp;                                                 \
        }

    // ---- Cox-de Boor, fully unrolled on registers ----
    float t0, t1, t2;
    float N0, N1, N2, N3, saved;

    // k=1
    TDIV(1.0f, A1, B2, t0);
    N0 = __fmul_rn(A1, t0);                                  // saved=0 + A1*t
    N1 = __fmul_rn(B2, t0);
    // k=2
    TDIV(N0, A1, B1, t0);
    TDIV(N1, A2, B2, t1);
    N0    = __fmul_rn(A1, t0);
    saved = __fmul_rn(B1, t0);
    N1    = __fadd_rn(saved, __fmul_rn(A2, t1));
    N2    = __fmul_rn(B2, t1);
    // k=3
    TDIV(N0, A1, B0, t0);
    TDIV(N1, A2, B1, t1);
    TDIV(N2, A3, B2, t2);
    N0    = __fmul_rn(A1, t0);
    saved = __fmul_rn(B0, t0);
    N1    = __fadd_rn(saved, __fmul_rn(A2, t1));
    saved = __fmul_rn(B1, t1);
    N2    = __fadd_rn(saved, __fmul_rn(A3, t2));
    N3    = __fmul_rn(B2, t2);
    #undef TDIV

    // ---- gather 4 padded rows (ds_read_b128) and dot ----
    const float4 c0 = *(const float4*)&cp[(span - 3) * 4];
    const float4 c1 = *(const float4*)&cp[(span - 2) * 4];
    const float4 c2 = *(const float4*)&cp[(span - 1) * 4];
    const float4 c3 = *(const float4*)&cp[(span - 0) * 4];

    float acc0, acc1, acc2;
    acc0 = __fmul_rn(N0, c0.x);
    acc1 = __fmul_rn(N0, c0.y);
    acc2 = __fmul_rn(N0, c0.z);
    acc0 = __fadd_rn(acc0, __fmul_rn(N1, c1.x));
    acc1 = __fadd_rn(acc1, __fmul_rn(N1, c1.y));
    acc2 = __fadd_rn(acc2, __fmul_rn(N1, c1.z));
    acc0 = __fadd_rn(acc0, __fmul_rn(N2, c2.x));
    acc1 = __fadd_rn(acc1, __fmul_rn(N2, c2.y));
    acc2 = __fadd_rn(acc2, __fmul_rn(N2, c2.z));
    acc0 = __fadd_rn(acc0, __fmul_rn(N3, c3.x));
    acc1 = __fadd_rn(acc1, __fmul_rn(N3, c3.y));
    acc2 = __fadd_rn(acc2, __fmul_rn(N3, c3.z));

    float* o = out + ((size_t)b * T_N + t) * 3;
    o[0] = acc0;
    o[1] = acc1;
    o[2] = acc2;
}

extern "C" void kernel_launch(void* const* d_in, const int* in_sizes, int n_in,
                              void* d_out, int out_size, void* d_ws, size_t ws_size,
                              hipStream_t stream) {
    const float* ctrl  = (const float*)d_in[0];   // (4096, 128, 3) f32
    const float* knots = (const float*)d_in[1];   // (4096, 132)   f32
    float* out = (float*)d_out;                   // (4096, 256, 3) f32

    curve_eval_kernel<<<dim3(B_N), dim3(T_N), 0, stream>>>(ctrl, knots, out);
}

// Round 7
// 11.629 us; speedup vs baseline: 1.3556x; 1.0306x over previous
//
#include <hip/hip_runtime.h>

// CurveEval3: cubic B-spline curve evaluation, faithful to the NumPy
// reference (which has blowup-sensitive degenerate-knot regions).
// B=4096 curves, M=128 ctrl pts, p=3, OUT_DIM=256 samples, DIM=3. KNOTS=132.
//
// Bitwise-critical pieces (kept exact): u (np.linspace f64 semantics, here
// evaluated at COMPILE TIME into a .rodata table — bitwise identical),
// span selection (argmin FIRST-index tie-break), dU = (U1-u)+(u-U2) with
// _rn ops + dU==0.0f check. Division via v_rcp_f32 (1-ULP relative, safe
// under the 0.088 absmax threshold; verified absmax 0.0156 rounds 2-6).
//
// Round-3 structure (best measured, reproduced 11.87/11.99 µs) with two
// micro-trims: constexpr u-table (kills the f64 sequence) and a guard-free
// 7-step span search over [0,127] (index 128 provably never selected:
// cond(128) needs u > 1+1e-8, but u <= 1-1e-5).

#define B_N     4096
#define M_N     128
#define P_DEG   3
#define T_N     256
#define KNOTS_N 132

// u = np.linspace(1e-5, 1-1e-5, 256): f64 step arithmetic, f32 cast,
// endpoint pinned — computed at compile time with IEEE f64 semantics.
struct UTab { float v[T_N]; };
constexpr UTab make_utab() {
    UTab r{};
    const double start = 1e-5;
    const double stop  = 1.0 - 1e-5;
    const double step  = (stop - start) / 255.0;
    for (int i = 0; i < T_N; ++i) r.v[i] = (float)((double)i * step + start);
    r.v[T_N - 1] = (float)stop;
    return r;
}
__device__ constexpr UTab U_TAB = make_utab();

__global__ __launch_bounds__(256) void curve_eval_kernel(
    const float* __restrict__ ctrl,   // (B, M, 3)
    const float* __restrict__ knots,  // (B, 132)
    float* __restrict__ out)          // (B, 256, 3)
{
    __shared__ float Uk[KNOTS_N];        // 132 floats
    __shared__ float cp[M_N * 4];        // rows padded to 4 -> ds_read_b128

    const int b = blockIdx.x;
    const int t = threadIdx.x;

    // ---- staging (vectorized, coalesced) ----
    if (t < 33) {
        ((float4*)Uk)[t] = ((const float4*)(knots + (size_t)b * KNOTS_N))[t];
    }
    if (t < 96) {
        float4 v = ((const float4*)(ctrl + (size_t)b * (M_N * 3)))[t];
        int i = t * 4;
        cp[((i + 0) / 3) * 4 + (i + 0) % 3] = v.x;
        cp[((i + 1) / 3) * 4 + (i + 1) % 3] = v.y;
        cp[((i + 2) / 3) * 4 + (i + 2) % 3] = v.z;
        cp[((i + 3) / 3) * 4 + (i + 3) % 3] = v.w;
    }

    const float u = U_TAB.v[t];          // coalesced .rodata load

    __syncthreads();

    // ---- span: last i in [0,127] with fl(u - U[3+i]) > 1e-8 (true-prefix;
    // cond(0) always true since u >= 1e-5; i=128 never selectable).
    // Guard-free 7-step binary descent: max reachable lo = 64+...+1 = 127.
    int lo = 0;
    #pragma unroll
    for (int s = 64; s >= 1; s >>= 1) {
        const int cand = lo + s;
        if (__fsub_rn(u, Uk[P_DEG + cand]) > 1e-8f) lo = cand;
    }
    // np.argmin FIRST-index tie-break: walk back over bitwise-equal d.
    {
        const float dmin = __fsub_rn(u, Uk[P_DEG + lo]);
        while (lo > 0 && __fsub_rn(u, Uk[P_DEG + lo - 1]) == dmin) --lo;
    }
    const int span = lo + P_DEG;   // uspan, in [3, 127]

    // ---- knot window into registers (single LDS reads) ----
    const float w0 = Uk[span - 2];
    const float w1 = Uk[span - 1];
    const float w2 = Uk[span];
    const float w3 = Uk[span + 1];
    const float w4 = Uk[span + 2];
    const float w5 = Uk[span + 3];

    const float A1 = __fsub_rn(w3, u);   // U[s+1]-u
    const float A2 = __fsub_rn(w4, u);   // U[s+2]-u
    const float A3 = __fsub_rn(w5, u);   // U[s+3]-u
    const float B0 = __fsub_rn(u, w0);   // u-U[s-2]
    const float B1 = __fsub_rn(u, w1);   // u-U[s-1]
    const float B2 = __fsub_rn(u, w2);   // u-U[s]

    // temp = (dU==0) ? 1e-4 : N * rcp(dU)   (division via v_rcp_f32)
    #define TDIV(N_, a1_, a2_, OUT_)                                    \
        {                                                               \
            const float dU = __fadd_rn(a1_, a2_);                       \
            float tmp = __fmul_rn((N_), __builtin_amdgcn_rcpf(dU));     \
            if (dU == 0.0f) tmp = 1e-4f;                                \
            OUT_ = tmp;                                                 \
        }

    // ---- Cox-de Boor, fully unrolled on registers ----
    float t0, t1, t2;
    float N0, N1, N2, N3, saved;

    // k=1
    TDIV(1.0f, A1, B2, t0);
    N0 = __fmul_rn(A1, t0);
    N1 = __fmul_rn(B2, t0);
    // k=2
    TDIV(N0, A1, B1, t0);
    TDIV(N1, A2, B2, t1);
    N0    = __fmul_rn(A1, t0);
    saved = __fmul_rn(B1, t0);
    N1    = __fadd_rn(saved, __fmul_rn(A2, t1));
    N2    = __fmul_rn(B2, t1);
    // k=3
    TDIV(N0, A1, B0, t0);
    TDIV(N1, A2, B1, t1);
    TDIV(N2, A3, B2, t2);
    N0    = __fmul_rn(A1, t0);
    saved = __fmul_rn(B0, t0);
    N1    = __fadd_rn(saved, __fmul_rn(A2, t1));
    saved = __fmul_rn(B1, t1);
    N2    = __fadd_rn(saved, __fmul_rn(A3, t2));
    N3    = __fmul_rn(B2, t2);
    #undef TDIV

    // ---- gather 4 padded rows (ds_read_b128) and dot ----
    const float4 c0 = *(const float4*)&cp[(span - 3) * 4];
    const float4 c1 = *(const float4*)&cp[(span - 2) * 4];
    const float4 c2 = *(const float4*)&cp[(span - 1) * 4];
    const float4 c3 = *(const float4*)&cp[(span - 0) * 4];

    float acc0, acc1, acc2;
    acc0 = __fmul_rn(N0, c0.x);
    acc1 = __fmul_rn(N0, c0.y);
    acc2 = __fmul_rn(N0, c0.z);
    acc0 = __fadd_rn(acc0, __fmul_rn(N1, c1.x));
    acc1 = __fadd_rn(acc1, __fmul_rn(N1, c1.y));
    acc2 = __fadd_rn(acc2, __fmul_rn(N1, c1.z));
    acc0 = __fadd_rn(acc0, __fmul_rn(N2, c2.x));
    acc1 = __fadd_rn(acc1, __fmul_rn(N2, c2.y));
    acc2 = __fadd_rn(acc2, __fmul_rn(N2, c2.z));
    acc0 = __fadd_rn(acc0, __fmul_rn(N3, c3.x));
    acc1 = __fadd_rn(acc1, __fmul_rn(N3, c3.y));
    acc2 = __fadd_rn(acc2, __fmul_rn(N3, c3.z));

    float* o = out + ((size_t)b * T_N + t) * 3;
    o[0] = acc0;
    o[1] = acc1;
    o[2] = acc2;
}

extern "C" void kernel_launch(void* const* d_in, const int* in_sizes, int n_in,
                              void* d_out, int out_size, void* d_ws, size_t ws_size,
                              hipStream_t stream) {
    const float* ctrl  = (const float*)d_in[0];   // (4096, 128, 3) f32
    const float* knots = (const float*)d_in[1];   // (4096, 132)   f32
    float* out = (float*)d_out;                   // (4096, 256, 3) f32

    curve_eval_kernel<<<dim3(B_N), dim3(T_N), 0, stream>>>(ctrl, knots, out);
}